// Round 8
// baseline (8868.233 us; speedup 1.0000x reference)
//
#include <hip/hip_runtime.h>
#include <math.h>

// Deep ESN, fp32, persistent wavefront-pipelined kernel, round 15.
// R14 (pipeline depth 16) was NULL vs R13's depth 8 -> per-wave MALL latency
// is covered; reverted to D=8. New diagnosis: Wlds weight reads were a
// ~16-way LDS bank conflict the whole time -- lane (kq,bh) reads float
// offset 16*k + 8*bh, bank = (16kq+8bh)%32 which lands ALL 64 lanes on
// banks {0,8,16,24} (SQ_LDS_BANK_CONFLICT 2.56e8 ~= 0.8us/tick/CU + the
// ds_read queuing latency it adds with only 2 waves/SIMD to hide it).
// R15: ONE change -- Wlds row stride 16 -> 17 floats. bank = (17kq+8bh)%32;
// gcd(17,32)=1 so each 32-lane bh-group covers all 32 banks exactly once ->
// 2 lanes/bank (free on CDNA4). LDS 136KB+2KB < 160KB, still 1 block/CU.

#define TT    512
#define RDIM  1024
#define EDIM  256
#define NL    4
#define BB    32
#define NBLK  256          // 64 blocks per layer
#define JW    16           // output columns per block
#define WSTR  17           // Wlds row stride in floats (bank-conflict-free)
#define HDIM  (RDIM * NL)  // 4096
#define NPAN  4            // 4 panels of 8 batch rows
#define CSTRIDE 32         // dwords between counter words (128B lines)

#define S_ELEMS   (2 * NL * NPAN * RDIM * 8)   // 2 parities, 1MB
#define FIN_ELEMS (BB * HDIM)

typedef float vf2 __attribute__((ext_vector_type(2)));
typedef float vf4 __attribute__((ext_vector_type(4)));

__device__ __forceinline__ float dpp_xor1(float x) {   // lane ^ 1
    return __int_as_float(__builtin_amdgcn_mov_dpp(__float_as_int(x), 0xB1, 0xF, 0xF, true));
}
__device__ __forceinline__ float dpp_xor2(float x) {   // lane ^ 2
    return __int_as_float(__builtin_amdgcn_mov_dpp(__float_as_int(x), 0x4E, 0xF, 0xF, true));
}

// 16B coherent load (bypass L1+L2 -> MALL), issue only, no wait.
__device__ __forceinline__ void gload_sc(vf4& d, const void* p) {
    asm volatile("global_load_dwordx4 %0, %1, off sc0 sc1" : "=v"(d) : "v"(p));
}
// 16B plain cached load (xe: read-only input, L2-cacheable), issue only.
__device__ __forceinline__ void gload_pl(vf4& d, const void* p) {
    asm volatile("global_load_dwordx4 %0, %1, off" : "=v"(d) : "v"(p));
}
// Counted wait, data-tied to the buffer being consumed.
__device__ __forceinline__ void vwait(int wn, vf4& r) {
    if (wn >= 7)      asm volatile("s_waitcnt vmcnt(7)" : "+v"(r));
    else if (wn == 6) asm volatile("s_waitcnt vmcnt(6)" : "+v"(r));
    else if (wn == 5) asm volatile("s_waitcnt vmcnt(5)" : "+v"(r));
    else if (wn == 4) asm volatile("s_waitcnt vmcnt(4)" : "+v"(r));
    else if (wn == 3) asm volatile("s_waitcnt vmcnt(3)" : "+v"(r));
    else if (wn == 2) asm volatile("s_waitcnt vmcnt(2)" : "+v"(r));
    else if (wn == 1) asm volatile("s_waitcnt vmcnt(1)" : "+v"(r));
    else              asm volatile("s_waitcnt vmcnt(0)" : "+v"(r));
}

// ---------------------------------------------------------------- gather ----
// xe[t][panel][k][8b] : panel layout matching reservoir reads
__global__ void gather_kernel(const int* __restrict__ x,
                              const float* __restrict__ embed,
                              float* __restrict__ xe)
{
    __shared__ int   ids[BB];
    __shared__ float sh[BB * (EDIM + 1)];
    const int t = blockIdx.x, tid = threadIdx.x;
    if (tid < BB) ids[tid] = x[tid * TT + t];
    __syncthreads();
    for (int r = 0; r < BB; ++r)
        sh[r * (EDIM + 1) + tid] = embed[ids[r] * EDIM + tid];
    __syncthreads();
    for (int i = tid; i < NPAN * EDIM * 8; i += 256) {
        int p = i >> 11, k = (i >> 3) & (EDIM - 1), bo = i & 7;
        xe[(size_t)t * (NPAN * EDIM * 8) + i] = sh[(p * 8 + bo) * (EDIM + 1) + k];
    }
}

// ------------------------------------------------- per-tick compute body ----
// Depth-8 pipelined MALL loads + pk-fma consume. All indices compile-time.
template<int KIN, bool SCIN>
__device__ __forceinline__ void tick_body(
    const float* __restrict__ Sown, const float* __restrict__ Sin,
    const float* __restrict__ Wlds,
    const int kh, const int lam, const int kq, const int bh,
    vf2 acc[4][8])
{
    constexpr int NOWN = RDIM / 64;     // 16 iters of 16B per lane
    constexpr int NIN  = KIN / 64;      // 16 (state) or 4 (xe)
    constexpr int NT   = NOWN + NIN;

    const vf4* ownp = (const vf4*)Sown;
    const vf4* inp  = (const vf4*)Sin;

    vf4 b[8];

    // prologue: fill the 8-deep queue (first 8 loads are all own-segment)
    #pragma unroll
    for (int i = 0; i < 8; ++i)
        gload_sc(b[i], (const void*)(ownp + (size_t)(kh * NOWN + i) * 64 + lam));

    #pragma unroll
    for (int i = 0; i < NT; ++i) {
        vf4& br = b[i & 7];
        const int wn = (NT - 1 - i) < 7 ? (NT - 1 - i) : 7;
        vwait(wn, br);
        const vf4 v = br;
        if (i + 8 < NT) {
            const int n = i + 8;
            if (n < NOWN) {
                gload_sc(br, (const void*)(ownp + (size_t)(kh * NOWN + n) * 64 + lam));
            } else {
                const void* p = (const void*)(inp + (size_t)(kh * NIN + (n - NOWN)) * 64 + lam);
                if (SCIN) gload_sc(br, p);
                else      gload_pl(br, p);
            }
        }
        const int k = (i < NOWN) ? ((kh * NOWN + i) * 32 + kq)
                                 : (RDIM + (kh * NIN + (i - NOWN)) * 32 + kq);
        const float* wr = &Wlds[k * WSTR + bh * 8];
        float4 wo0 = *(const float4*)wr;
        float4 wo1 = *(const float4*)(wr + 4);
        vf2 wv[8];
        wv[0] = (vf2){wo0.x, wo0.y}; wv[1] = (vf2){wo0.z, wo0.w};
        wv[2] = (vf2){wo1.x, wo1.y}; wv[3] = (vf2){wo1.z, wo1.w};
        wv[4] = (vf2){dpp_xor1(wo0.x), dpp_xor1(wo0.y)};
        wv[5] = (vf2){dpp_xor1(wo0.z), dpp_xor1(wo0.w)};
        wv[6] = (vf2){dpp_xor1(wo1.x), dpp_xor1(wo1.y)};
        wv[7] = (vf2){dpp_xor1(wo1.z), dpp_xor1(wo1.w)};
        const float vv[4] = {v[0], v[1], v[2], v[3]};
        #pragma unroll
        for (int q = 0; q < 4; ++q) {
            vf2 s = {vv[q], vv[q]};
            #pragma unroll
            for (int jp = 0; jp < 8; ++jp) acc[q][jp] += s * wv[jp];
        }
    }
}

// ------------------------------------------------------------- reservoir ----
__global__ __launch_bounds__(512, 2) void reservoir_kernel(
    const float* __restrict__ Win0, const float* __restrict__ WinR,
    const float* __restrict__ Rst,  const float* __restrict__ xe,
    float* __restrict__ S, float* __restrict__ Fin,
    unsigned* __restrict__ cnt, unsigned* __restrict__ rel)
{
    __shared__ float Wlds[2048 * WSTR];     // 136 KB, row k = 17 floats (swizzled)
    __shared__ float Pbuf[NPAN * JW * 8];   // 2 KB, cross-wave k partials
    const int tid   = threadIdx.x;
    const int blk   = blockIdx.x;
    const int layer = blk >> 6;
    const int j0    = (blk & 63) * JW;
    const int Kin   = (layer == 0) ? EDIM : RDIM;

    // rows [0,1024) = R_stack col-slice, rows [1024,1024+Kin) = Win col-slice
    for (int idx = tid; idx < (RDIM + Kin) * JW; idx += 512) {
        int k = idx >> 4, j = idx & 15;
        float wv;
        if (k < RDIM) wv = Rst[((size_t)layer * RDIM + k) * RDIM + j0 + j];
        else {
            int k2 = k - RDIM;
            wv = (layer == 0) ? Win0[(size_t)k2 * RDIM + j0 + j]
                              : WinR[((size_t)(layer - 1) * RDIM + k2) * RDIM + j0 + j];
        }
        Wlds[k * WSTR + j] = wv;
    }
    __syncthreads();

    const int w8  = tid >> 6;   // 8 waves
    const int w   = w8 & 3;     // panel (8 batch rows)
    const int kh  = w8 >> 2;    // k-half: wave reads a disjoint k-slice
    const int lam = tid & 63;
    const int kq  = lam >> 1;   // 32-way k split within wave
    const int bh  = lam & 1;    // which float4 of the 8-wide batch row
    const int bh4 = bh * 4;

    for (int tick = 0; tick < TT + NL - 1; ++tick) {
        const int t = tick - layer;
        if (t >= 0 && t < TT) {
            const int cur = tick & 1, prv = (tick - 1) & 1;
            const float* Sown = S + (((size_t)(prv * NL + layer)) * NPAN + w) * RDIM * 8;
            const float* Sin  = (layer == 0)
                ? (xe + ((size_t)t * NPAN + w) * (EDIM * 8))
                : (S + (((size_t)(prv * NL + layer - 1)) * NPAN + w) * RDIM * 8);

            vf2 acc[4][8];
            #pragma unroll
            for (int i = 0; i < 4; ++i)
                #pragma unroll
                for (int jp = 0; jp < 8; ++jp) acc[i][jp] = (vf2)(0.f);

            if (layer == 0) tick_body<EDIM, false>(Sown, Sin, Wlds, kh, lam, kq, bh, acc);
            else            tick_body<RDIM, true >(Sown, Sin, Wlds, kh, lam, kq, bh, acc);

            // ---- reduce-scatter over kq: 64 accs -> 2 partials per lane ----
            float r64v[64];
            #pragma unroll
            for (int i = 0; i < 4; ++i)
                #pragma unroll
                for (int jp = 0; jp < 8; ++jp) {
                    r64v[(i << 4) | (jp << 1)]     = acc[i][jp].x;
                    r64v[(i << 4) | (jp << 1) | 1] = acc[i][jp].y;
                }
            float r32v[32], r16v[16], r8v[8], r4v[4], rfin[2];
            {   const bool myb = kq & 1;                 // stage 0: DPP xor2
                #pragma unroll
                for (int m = 0; m < 32; ++m) {
                    float a = r64v[2 * m], b = r64v[2 * m + 1];
                    float send = myb ? a : b, keep = myb ? b : a;
                    r32v[m] = keep + dpp_xor2(send);
                }
            }
            {   const bool myb = (kq >> 1) & 1;          // stage 1: xor 4
                #pragma unroll
                for (int m = 0; m < 16; ++m) {
                    float a = r32v[2 * m], b = r32v[2 * m + 1];
                    float send = myb ? a : b, keep = myb ? b : a;
                    r16v[m] = keep + __shfl_xor(send, 4, 64);
                }
            }
            {   const bool myb = (kq >> 2) & 1;          // stage 2: xor 8
                #pragma unroll
                for (int m = 0; m < 8; ++m) {
                    float a = r16v[2 * m], b = r16v[2 * m + 1];
                    float send = myb ? a : b, keep = myb ? b : a;
                    r8v[m] = keep + __shfl_xor(send, 8, 64);
                }
            }
            {   const bool myb = (kq >> 3) & 1;          // stage 3: xor 16
                #pragma unroll
                for (int m = 0; m < 4; ++m) {
                    float a = r8v[2 * m], b = r8v[2 * m + 1];
                    float send = myb ? a : b, keep = myb ? b : a;
                    r4v[m] = keep + __shfl_xor(send, 16, 64);
                }
            }
            {   const bool myb = (kq >> 4) & 1;          // stage 4: xor 32
                #pragma unroll
                for (int m = 0; m < 2; ++m) {
                    float a = r4v[2 * m], b = r4v[2 * m + 1];
                    float send = myb ? a : b, keep = myb ? b : a;
                    rfin[m] = keep + __shfl_xor(send, 32, 64);
                }
            }

            // ---- cross-wave k-half combine via LDS, then epilogue ----
            const int i0 = kq >> 4;                 // 0..1
            const int cc = kq & 15;
            const int j  = (cc & 7) + 8 * (bh ^ (cc >> 3));   // logical col
            if (kh) {                               // k-half 1: publish partial
                #pragma unroll
                for (int m = 0; m < 2; ++m)
                    Pbuf[(w * JW + j) * 8 + (bh4 + i0 + 2 * m)] = rfin[m];
            }
            __syncthreads();                        // block-uniform (t uniform)
            if (!kh) {                              // k-half 0: combine + store
                float* sbase = S + (((size_t)(cur * NL + layer)) * NPAN + w) * RDIM * 8
                                 + (size_t)(j0 + j) * 8;
                #pragma unroll
                for (int m = 0; m < 2; ++m) {
                    const int bi = bh4 + i0 + 2 * m;    // slot within panel's 8
                    const float o = tanhf(rfin[m] + Pbuf[(w * JW + j) * 8 + bi]);
                    // sc1 store: direct to MALL, drained by pre-barrier vmcnt(0)
                    __hip_atomic_store(sbase + bi, o, __ATOMIC_RELAXED, __HIP_MEMORY_SCOPE_AGENT);
                    if (t == TT - 1)
                        Fin[(size_t)(w * 8 + bi) * HDIM + layer * RDIM + j0 + j] = o;
                }
            }
        }
        // ---- grid barrier v3: spread arrive, single summer, replicated
        //      release lines, 1-lane backoff polls (no poll storm) ----
        __syncthreads();                          // drains all waves' stores
        if (tid == 0)
            __hip_atomic_fetch_add(&cnt[(blk & 15) * CSTRIDE], 1u,
                                   __ATOMIC_RELAXED, __HIP_MEMORY_SCOPE_AGENT);
        const unsigned wrel = (unsigned)(tick + 1);
        if (blk == 0) {
            if (tid < 64) {                       // summer wave
                const unsigned wsum = wrel * (unsigned)NBLK;
                int guard = 0;
                for (;;) {
                    unsigned v = 0;
                    if (lam < 16)
                        v = __hip_atomic_load(&cnt[lam * CSTRIDE],
                                              __ATOMIC_RELAXED, __HIP_MEMORY_SCOPE_AGENT);
                    #pragma unroll
                    for (int m = 1; m <= 32; m <<= 1) v += __shfl_xor(v, m, 64);
                    if (v >= wsum) break;         // v is total on ALL lanes
                    __builtin_amdgcn_s_sleep(2);
                    if (++guard > (1 << 16)) break;   // safety valve
                }
                if (lam < 16)                     // publish release, 16 copies
                    __hip_atomic_store(&rel[lam * CSTRIDE], wrel,
                                       __ATOMIC_RELAXED, __HIP_MEMORY_SCOPE_AGENT);
            }
        } else {
            if (tid == 0) {                       // one poller lane per block
                int guard = 0;
                while (__hip_atomic_load(&rel[(blk & 15) * CSTRIDE],
                                         __ATOMIC_RELAXED, __HIP_MEMORY_SCOPE_AGENT) < wrel) {
                    __builtin_amdgcn_s_sleep(4);
                    if (++guard > (1 << 16)) break;   // safety valve
                }
            }
        }
        __syncthreads();
    }
}

// ------------------------------------------------------------- layernorm ----
__global__ void ln_kernel(const float* __restrict__ Fin,
                          const float* __restrict__ gamma,
                          const float* __restrict__ beta,
                          float* __restrict__ out)
{
    const int r = blockIdx.x, tid = threadIdx.x;
    const float* row = Fin + (size_t)r * HDIM;
    float s = 0.f, s2 = 0.f;
    for (int i = tid; i < HDIM; i += 256) { float v = row[i]; s += v; s2 += v * v; }
    for (int off = 32; off; off >>= 1) {
        s  += __shfl_down(s,  off, 64);
        s2 += __shfl_down(s2, off, 64);
    }
    __shared__ float rs[4], rs2[4];
    __shared__ float mu_s, rstd_s;
    if ((tid & 63) == 0) { rs[tid >> 6] = s; rs2[tid >> 6] = s2; }
    __syncthreads();
    if (tid == 0) {
        float S1 = rs[0] + rs[1] + rs[2] + rs[3];
        float S2 = rs2[0] + rs2[1] + rs2[2] + rs2[3];
        float mu = S1 / (float)HDIM;
        float var = S2 / (float)HDIM - mu * mu;
        mu_s = mu; rstd_s = rsqrtf(var + 1e-5f);
    }
    __syncthreads();
    float mu = mu_s, rstd = rstd_s;
    for (int i = tid; i < HDIM; i += 256)
        out[(size_t)r * HDIM + i] = (row[i] - mu) * rstd * gamma[i] + beta[i];
}

// ----------------------------------------------------------------- launch ---
extern "C" void kernel_launch(void* const* d_in, const int* in_sizes, int n_in,
                              void* d_out, int out_size, void* d_ws, size_t ws_size,
                              hipStream_t stream)
{
    const int*   x     = (const int*)d_in[0];
    const float* embed = (const float*)d_in[1];
    const float* Win0  = (const float*)d_in[2];
    const float* WinR  = (const float*)d_in[3];
    const float* Rst   = (const float*)d_in[4];
    const float* gamma = (const float*)d_in[5];
    const float* beta  = (const float*)d_in[6];
    float* out = (float*)d_out;

    char* ws = (char*)d_ws;
    unsigned* cnt = (unsigned*)ws;                    // 16 lines (arrive)
    unsigned* rel = cnt + 16 * CSTRIDE;               // 16 lines (release)
    float* S   = (float*)(ws + 8192);                                // 1MB
    float* Fin = S + S_ELEMS;                                        // 0.5MB
    float* xe  = Fin + FIN_ELEMS;                                    // 16.8MB

    hipMemsetAsync(ws, 0, 8192 + (size_t)S_ELEMS * 4, stream);       // flags+states
    gather_kernel   <<<TT,   256, 0, stream>>>(x, embed, xe);
    reservoir_kernel<<<NBLK, 512, 0, stream>>>(Win0, WinR, Rst, xe, S, Fin, cnt, rel);
    ln_kernel       <<<BB,   256, 0, stream>>>(Fin, gamma, beta, out);
}

// Round 9
// 4657.450 us; speedup vs baseline: 1.9041x; 1.9041x over previous
//
#include <hip/hip_runtime.h>
#include <math.h>

// Deep ESN, fp32, persistent wavefront-pipelined kernel, round 16.
// R15 (stride 17) proved the Wlds bank-conflict diagnosis (2.56e8 -> 1.28e7)
// but broke 16B alignment -> compiler split ds_read_b128 into b32s -> 8868us.
// R16: stride stays 16 (alignment preserved, b128 restored); bank spread via
// XOR SLOT swizzle instead: row k's logical float4 slot s lives at physical
// slot s ^ ((k>>1)&3). Start-quad (4k + slot) mod 8 then covers all 8 values
// uniformly across the wave -> 8 accesses/bank = minimum (conflict-free).
// (k>>1)&3 == (kq>>1)&3 is per-lane constant -> offsets hoisted out of the
// loop; inner loop is byte-identical in structure to R13 (D=8, 4840us).

#define TT    512
#define RDIM  1024
#define EDIM  256
#define NL    4
#define BB    32
#define NBLK  256          // 64 blocks per layer
#define JW    16           // output columns per block
#define HDIM  (RDIM * NL)  // 4096
#define NPAN  4            // 4 panels of 8 batch rows
#define CSTRIDE 32         // dwords between counter words (128B lines)

#define S_ELEMS   (2 * NL * NPAN * RDIM * 8)   // 2 parities, 1MB
#define FIN_ELEMS (BB * HDIM)

typedef float vf2 __attribute__((ext_vector_type(2)));
typedef float vf4 __attribute__((ext_vector_type(4)));

__device__ __forceinline__ float dpp_xor1(float x) {   // lane ^ 1
    return __int_as_float(__builtin_amdgcn_mov_dpp(__float_as_int(x), 0xB1, 0xF, 0xF, true));
}
__device__ __forceinline__ float dpp_xor2(float x) {   // lane ^ 2
    return __int_as_float(__builtin_amdgcn_mov_dpp(__float_as_int(x), 0x4E, 0xF, 0xF, true));
}

// 16B coherent load (bypass L1+L2 -> MALL), issue only, no wait.
__device__ __forceinline__ void gload_sc(vf4& d, const void* p) {
    asm volatile("global_load_dwordx4 %0, %1, off sc0 sc1" : "=v"(d) : "v"(p));
}
// 16B plain cached load (xe: read-only input, L2-cacheable), issue only.
__device__ __forceinline__ void gload_pl(vf4& d, const void* p) {
    asm volatile("global_load_dwordx4 %0, %1, off" : "=v"(d) : "v"(p));
}
// Counted wait, data-tied to the buffer being consumed.
__device__ __forceinline__ void vwait(int wn, vf4& r) {
    if (wn >= 7)      asm volatile("s_waitcnt vmcnt(7)" : "+v"(r));
    else if (wn == 6) asm volatile("s_waitcnt vmcnt(6)" : "+v"(r));
    else if (wn == 5) asm volatile("s_waitcnt vmcnt(5)" : "+v"(r));
    else if (wn == 4) asm volatile("s_waitcnt vmcnt(4)" : "+v"(r));
    else if (wn == 3) asm volatile("s_waitcnt vmcnt(3)" : "+v"(r));
    else if (wn == 2) asm volatile("s_waitcnt vmcnt(2)" : "+v"(r));
    else if (wn == 1) asm volatile("s_waitcnt vmcnt(1)" : "+v"(r));
    else              asm volatile("s_waitcnt vmcnt(0)" : "+v"(r));
}

// ---------------------------------------------------------------- gather ----
// xe[t][panel][k][8b] : panel layout matching reservoir reads
__global__ void gather_kernel(const int* __restrict__ x,
                              const float* __restrict__ embed,
                              float* __restrict__ xe)
{
    __shared__ int   ids[BB];
    __shared__ float sh[BB * (EDIM + 1)];
    const int t = blockIdx.x, tid = threadIdx.x;
    if (tid < BB) ids[tid] = x[tid * TT + t];
    __syncthreads();
    for (int r = 0; r < BB; ++r)
        sh[r * (EDIM + 1) + tid] = embed[ids[r] * EDIM + tid];
    __syncthreads();
    for (int i = tid; i < NPAN * EDIM * 8; i += 256) {
        int p = i >> 11, k = (i >> 3) & (EDIM - 1), bo = i & 7;
        xe[(size_t)t * (NPAN * EDIM * 8) + i] = sh[(p * 8 + bo) * (EDIM + 1) + k];
    }
}

// ------------------------------------------------- per-tick compute body ----
// Depth-8 pipelined MALL loads + pk-fma consume. All indices compile-time.
// so0/so1: per-lane XOR-swizzled float offsets of the two float4 slots.
template<int KIN, bool SCIN>
__device__ __forceinline__ void tick_body(
    const float* __restrict__ Sown, const float* __restrict__ Sin,
    const float* __restrict__ Wlds,
    const int kh, const int lam, const int kq, const int so0, const int so1,
    vf2 acc[4][8])
{
    constexpr int NOWN = RDIM / 64;     // 16 iters of 16B per lane
    constexpr int NIN  = KIN / 64;      // 16 (state) or 4 (xe)
    constexpr int NT   = NOWN + NIN;

    const vf4* ownp = (const vf4*)Sown;
    const vf4* inp  = (const vf4*)Sin;

    vf4 b[8];

    // prologue: fill the 8-deep queue (first 8 loads are all own-segment)
    #pragma unroll
    for (int i = 0; i < 8; ++i)
        gload_sc(b[i], (const void*)(ownp + (size_t)(kh * NOWN + i) * 64 + lam));

    #pragma unroll
    for (int i = 0; i < NT; ++i) {
        vf4& br = b[i & 7];
        const int wn = (NT - 1 - i) < 7 ? (NT - 1 - i) : 7;
        vwait(wn, br);
        const vf4 v = br;
        if (i + 8 < NT) {
            const int n = i + 8;
            if (n < NOWN) {
                gload_sc(br, (const void*)(ownp + (size_t)(kh * NOWN + n) * 64 + lam));
            } else {
                const void* p = (const void*)(inp + (size_t)(kh * NIN + (n - NOWN)) * 64 + lam);
                if (SCIN) gload_sc(br, p);
                else      gload_pl(br, p);
            }
        }
        const int k = (i < NOWN) ? ((kh * NOWN + i) * 32 + kq)
                                 : (RDIM + (kh * NIN + (i - NOWN)) * 32 + kq);
        const float* wrow = &Wlds[k * JW];
        float4 wo0 = *(const float4*)(wrow + so0);
        float4 wo1 = *(const float4*)(wrow + so1);
        vf2 wv[8];
        wv[0] = (vf2){wo0.x, wo0.y}; wv[1] = (vf2){wo0.z, wo0.w};
        wv[2] = (vf2){wo1.x, wo1.y}; wv[3] = (vf2){wo1.z, wo1.w};
        wv[4] = (vf2){dpp_xor1(wo0.x), dpp_xor1(wo0.y)};
        wv[5] = (vf2){dpp_xor1(wo0.z), dpp_xor1(wo0.w)};
        wv[6] = (vf2){dpp_xor1(wo1.x), dpp_xor1(wo1.y)};
        wv[7] = (vf2){dpp_xor1(wo1.z), dpp_xor1(wo1.w)};
        const float vv[4] = {v[0], v[1], v[2], v[3]};
        #pragma unroll
        for (int q = 0; q < 4; ++q) {
            vf2 s = {vv[q], vv[q]};
            #pragma unroll
            for (int jp = 0; jp < 8; ++jp) acc[q][jp] += s * wv[jp];
        }
    }
}

// ------------------------------------------------------------- reservoir ----
__global__ __launch_bounds__(512, 2) void reservoir_kernel(
    const float* __restrict__ Win0, const float* __restrict__ WinR,
    const float* __restrict__ Rst,  const float* __restrict__ xe,
    float* __restrict__ S, float* __restrict__ Fin,
    unsigned* __restrict__ cnt, unsigned* __restrict__ rel)
{
    __shared__ float Wlds[2048 * JW];       // 128 KB, row k = 4 slot-swizzled float4s
    __shared__ float Pbuf[NPAN * JW * 8];   // 2 KB, cross-wave k partials
    const int tid   = threadIdx.x;
    const int blk   = blockIdx.x;
    const int layer = blk >> 6;
    const int j0    = (blk & 63) * JW;
    const int Kin   = (layer == 0) ? EDIM : RDIM;

    // rows [0,1024) = R_stack col-slice, rows [1024,1024+Kin) = Win col-slice
    // slot swizzle: logical float4 slot s of row k stored at s ^ ((k>>1)&3)
    for (int idx = tid; idx < (RDIM + Kin) * JW; idx += 512) {
        int k = idx >> 4, j = idx & 15;
        float wv;
        if (k < RDIM) wv = Rst[((size_t)layer * RDIM + k) * RDIM + j0 + j];
        else {
            int k2 = k - RDIM;
            wv = (layer == 0) ? Win0[(size_t)k2 * RDIM + j0 + j]
                              : WinR[((size_t)(layer - 1) * RDIM + k2) * RDIM + j0 + j];
        }
        Wlds[(k << 4) + (((j >> 2) ^ ((k >> 1) & 3)) << 2) + (j & 3)] = wv;
    }
    __syncthreads();

    const int w8  = tid >> 6;   // 8 waves
    const int w   = w8 & 3;     // panel (8 batch rows)
    const int kh  = w8 >> 2;    // k-half: wave reads a disjoint k-slice
    const int lam = tid & 63;
    const int kq  = lam >> 1;   // 32-way k split within wave
    const int bh  = lam & 1;    // which float4 of the 8-wide batch row
    const int bh4 = bh * 4;
    // per-lane swizzled slot offsets: (k>>1)&3 == (kq>>1)&3 for all k this
    // lane touches (k = 32*m + kq, and RDIM=1024 contributes 0 mod 4).
    const int xsw = (kq >> 1) & 3;
    const int so0 = ((2 * bh)     ^ xsw) << 2;
    const int so1 = ((2 * bh + 1) ^ xsw) << 2;

    for (int tick = 0; tick < TT + NL - 1; ++tick) {
        const int t = tick - layer;
        if (t >= 0 && t < TT) {
            const int cur = tick & 1, prv = (tick - 1) & 1;
            const float* Sown = S + (((size_t)(prv * NL + layer)) * NPAN + w) * RDIM * 8;
            const float* Sin  = (layer == 0)
                ? (xe + ((size_t)t * NPAN + w) * (EDIM * 8))
                : (S + (((size_t)(prv * NL + layer - 1)) * NPAN + w) * RDIM * 8);

            vf2 acc[4][8];
            #pragma unroll
            for (int i = 0; i < 4; ++i)
                #pragma unroll
                for (int jp = 0; jp < 8; ++jp) acc[i][jp] = (vf2)(0.f);

            if (layer == 0) tick_body<EDIM, false>(Sown, Sin, Wlds, kh, lam, kq, so0, so1, acc);
            else            tick_body<RDIM, true >(Sown, Sin, Wlds, kh, lam, kq, so0, so1, acc);

            // ---- reduce-scatter over kq: 64 accs -> 2 partials per lane ----
            float r64v[64];
            #pragma unroll
            for (int i = 0; i < 4; ++i)
                #pragma unroll
                for (int jp = 0; jp < 8; ++jp) {
                    r64v[(i << 4) | (jp << 1)]     = acc[i][jp].x;
                    r64v[(i << 4) | (jp << 1) | 1] = acc[i][jp].y;
                }
            float r32v[32], r16v[16], r8v[8], r4v[4], rfin[2];
            {   const bool myb = kq & 1;                 // stage 0: DPP xor2
                #pragma unroll
                for (int m = 0; m < 32; ++m) {
                    float a = r64v[2 * m], b = r64v[2 * m + 1];
                    float send = myb ? a : b, keep = myb ? b : a;
                    r32v[m] = keep + dpp_xor2(send);
                }
            }
            {   const bool myb = (kq >> 1) & 1;          // stage 1: xor 4
                #pragma unroll
                for (int m = 0; m < 16; ++m) {
                    float a = r32v[2 * m], b = r32v[2 * m + 1];
                    float send = myb ? a : b, keep = myb ? b : a;
                    r16v[m] = keep + __shfl_xor(send, 4, 64);
                }
            }
            {   const bool myb = (kq >> 2) & 1;          // stage 2: xor 8
                #pragma unroll
                for (int m = 0; m < 8; ++m) {
                    float a = r16v[2 * m], b = r16v[2 * m + 1];
                    float send = myb ? a : b, keep = myb ? b : a;
                    r8v[m] = keep + __shfl_xor(send, 8, 64);
                }
            }
            {   const bool myb = (kq >> 3) & 1;          // stage 3: xor 16
                #pragma unroll
                for (int m = 0; m < 4; ++m) {
                    float a = r8v[2 * m], b = r8v[2 * m + 1];
                    float send = myb ? a : b, keep = myb ? b : a;
                    r4v[m] = keep + __shfl_xor(send, 16, 64);
                }
            }
            {   const bool myb = (kq >> 4) & 1;          // stage 4: xor 32
                #pragma unroll
                for (int m = 0; m < 2; ++m) {
                    float a = r4v[2 * m], b = r4v[2 * m + 1];
                    float send = myb ? a : b, keep = myb ? b : a;
                    rfin[m] = keep + __shfl_xor(send, 32, 64);
                }
            }

            // ---- cross-wave k-half combine via LDS, then epilogue ----
            const int i0 = kq >> 4;                 // 0..1
            const int cc = kq & 15;
            const int j  = (cc & 7) + 8 * (bh ^ (cc >> 3));   // logical col
            if (kh) {                               // k-half 1: publish partial
                #pragma unroll
                for (int m = 0; m < 2; ++m)
                    Pbuf[(w * JW + j) * 8 + (bh4 + i0 + 2 * m)] = rfin[m];
            }
            __syncthreads();                        // block-uniform (t uniform)
            if (!kh) {                              // k-half 0: combine + store
                float* sbase = S + (((size_t)(cur * NL + layer)) * NPAN + w) * RDIM * 8
                                 + (size_t)(j0 + j) * 8;
                #pragma unroll
                for (int m = 0; m < 2; ++m) {
                    const int bi = bh4 + i0 + 2 * m;    // slot within panel's 8
                    const float o = tanhf(rfin[m] + Pbuf[(w * JW + j) * 8 + bi]);
                    // sc1 store: direct to MALL, drained by pre-barrier vmcnt(0)
                    __hip_atomic_store(sbase + bi, o, __ATOMIC_RELAXED, __HIP_MEMORY_SCOPE_AGENT);
                    if (t == TT - 1)
                        Fin[(size_t)(w * 8 + bi) * HDIM + layer * RDIM + j0 + j] = o;
                }
            }
        }
        // ---- grid barrier v3: spread arrive, single summer, replicated
        //      release lines, 1-lane backoff polls (no poll storm) ----
        __syncthreads();                          // drains all waves' stores
        if (tid == 0)
            __hip_atomic_fetch_add(&cnt[(blk & 15) * CSTRIDE], 1u,
                                   __ATOMIC_RELAXED, __HIP_MEMORY_SCOPE_AGENT);
        const unsigned wrel = (unsigned)(tick + 1);
        if (blk == 0) {
            if (tid < 64) {                       // summer wave
                const unsigned wsum = wrel * (unsigned)NBLK;
                int guard = 0;
                for (;;) {
                    unsigned v = 0;
                    if (lam < 16)
                        v = __hip_atomic_load(&cnt[lam * CSTRIDE],
                                              __ATOMIC_RELAXED, __HIP_MEMORY_SCOPE_AGENT);
                    #pragma unroll
                    for (int m = 1; m <= 32; m <<= 1) v += __shfl_xor(v, m, 64);
                    if (v >= wsum) break;         // v is total on ALL lanes
                    __builtin_amdgcn_s_sleep(2);
                    if (++guard > (1 << 16)) break;   // safety valve
                }
                if (lam < 16)                     // publish release, 16 copies
                    __hip_atomic_store(&rel[lam * CSTRIDE], wrel,
                                       __ATOMIC_RELAXED, __HIP_MEMORY_SCOPE_AGENT);
            }
        } else {
            if (tid == 0) {                       // one poller lane per block
                int guard = 0;
                while (__hip_atomic_load(&rel[(blk & 15) * CSTRIDE],
                                         __ATOMIC_RELAXED, __HIP_MEMORY_SCOPE_AGENT) < wrel) {
                    __builtin_amdgcn_s_sleep(4);
                    if (++guard > (1 << 16)) break;   // safety valve
                }
            }
        }
        __syncthreads();
    }
}

// ------------------------------------------------------------- layernorm ----
__global__ void ln_kernel(const float* __restrict__ Fin,
                          const float* __restrict__ gamma,
                          const float* __restrict__ beta,
                          float* __restrict__ out)
{
    const int r = blockIdx.x, tid = threadIdx.x;
    const float* row = Fin + (size_t)r * HDIM;
    float s = 0.f, s2 = 0.f;
    for (int i = tid; i < HDIM; i += 256) { float v = row[i]; s += v; s2 += v * v; }
    for (int off = 32; off; off >>= 1) {
        s  += __shfl_down(s,  off, 64);
        s2 += __shfl_down(s2, off, 64);
    }
    __shared__ float rs[4], rs2[4];
    __shared__ float mu_s, rstd_s;
    if ((tid & 63) == 0) { rs[tid >> 6] = s; rs2[tid >> 6] = s2; }
    __syncthreads();
    if (tid == 0) {
        float S1 = rs[0] + rs[1] + rs[2] + rs[3];
        float S2 = rs2[0] + rs2[1] + rs2[2] + rs2[3];
        float mu = S1 / (float)HDIM;
        float var = S2 / (float)HDIM - mu * mu;
        mu_s = mu; rstd_s = rsqrtf(var + 1e-5f);
    }
    __syncthreads();
    float mu = mu_s, rstd = rstd_s;
    for (int i = tid; i < HDIM; i += 256)
        out[(size_t)r * HDIM + i] = (row[i] - mu) * rstd * gamma[i] + beta[i];
}

// ----------------------------------------------------------------- launch ---
extern "C" void kernel_launch(void* const* d_in, const int* in_sizes, int n_in,
                              void* d_out, int out_size, void* d_ws, size_t ws_size,
                              hipStream_t stream)
{
    const int*   x     = (const int*)d_in[0];
    const float* embed = (const float*)d_in[1];
    const float* Win0  = (const float*)d_in[2];
    const float* WinR  = (const float*)d_in[3];
    const float* Rst   = (const float*)d_in[4];
    const float* gamma = (const float*)d_in[5];
    const float* beta  = (const float*)d_in[6];
    float* out = (float*)d_out;

    char* ws = (char*)d_ws;
    unsigned* cnt = (unsigned*)ws;                    // 16 lines (arrive)
    unsigned* rel = cnt + 16 * CSTRIDE;               // 16 lines (release)
    float* S   = (float*)(ws + 8192);                                // 1MB
    float* Fin = S + S_ELEMS;                                        // 0.5MB
    float* xe  = Fin + FIN_ELEMS;                                    // 16.8MB

    hipMemsetAsync(ws, 0, 8192 + (size_t)S_ELEMS * 4, stream);       // flags+states
    gather_kernel   <<<TT,   256, 0, stream>>>(x, embed, xe);
    reservoir_kernel<<<NBLK, 512, 0, stream>>>(Win0, WinR, Rst, xe, S, Fin, cnt, rel);
    ln_kernel       <<<BB,   256, 0, stream>>>(Fin, gamma, beta, out);
}